// Round 14
// baseline (133.774 us; speedup 1.0000x reference)
//
#include <hip/hip_runtime.h>
#include <math.h>

#define NPG 128      // nodes per graph
#define HID 64
#define ICH 151
#define EPG 2048     // edges per graph
#define KP  160      // W1T padded K (5 MFMA k-steps of 32)
#define ASS 132      // As row stride, f32 (528B: 16B-aligned, 2-way banks)
#define ATPB 512     // agg threads
#define AEPT (EPG / ATPB)

typedef __attribute__((ext_vector_type(8))) short  short8;   // bf16x8 frag
typedef __attribute__((ext_vector_type(4))) float  floatx4;  // f32x4 acc

// software fp32->bf16 RNE (proven R4/R6/R8/R10-R13; cvt_pk asm NaN'd R7/R9)
static __device__ __forceinline__ unsigned short f2bf(float v) {
    unsigned u = __builtin_bit_cast(unsigned, v);
    return (unsigned short)((u + 0x7fffu + ((u >> 16) & 1u)) >> 16);
}
static __device__ __forceinline__ unsigned packbf(float a, float b) {
    return (unsigned)f2bf(a) | ((unsigned)f2bf(b) << 16);
}
static __device__ __forceinline__ short8 pack8(const float* v) {
    union { unsigned u[4]; short8 s; } r;
    r.u[0] = packbf(v[0], v[1]);
    r.u[1] = packbf(v[2], v[3]);
    r.u[2] = packbf(v[4], v[5]);
    r.u[3] = packbf(v[6], v[7]);
    return r.s;
}

// ---- prep: W1 [151][64] f32 -> W1T [64][160] bf16 (k-pad zeroed) ----
__global__ __launch_bounds__(512) void gcn_prep(const float* __restrict__ W1,
                                                short* __restrict__ W1T) {
    int i = threadIdx.x + blockIdx.x * 512;          // 10240 elements exactly
    if (i < HID * KP) {
        int ch = i / KP, k = i - ch * KP;
        W1T[i] = (short)f2bf((k < ICH) ? W1[k * HID + ch] : 0.0f);
    }
}

// ---- kernel 1: h = bf16(x) @ bf16(W1) -> hg[g][ch][node] bf16 ----
// ZERO LDS, ZERO barriers: every wave independent (16 rows x 64 ch).
__global__ __launch_bounds__(256, 4) void gcn_gemm(
    const float* __restrict__ x,       // [N,151]
    const short* __restrict__ W1T,     // [64][160] bf16
    short* __restrict__ hg)            // [B][64][128] bf16
{
    const int t    = threadIdx.x;
    const int lane = t & 63;
    const int wv   = t >> 6;                          // 0..3
    const int c16  = lane & 15;
    const int kq   = (lane >> 4) * 8;

    const int gw  = blockIdx.x * 4 + wv;              // global wave id
    const int g   = gw >> 3;                          // graph
    const int sub = gw & 7;                           // 16-row group

    // x A-fragments: direct guarded scalar loads (proven best)
    short8 af[5];
    {
        const float* xr = x + ((size_t)g * NPG + sub * 16 + c16) * ICH;
        #pragma unroll
        for (int s = 0; s < 5; ++s) {
            float v[8];
            #pragma unroll
            for (int j = 0; j < 8; ++j) {
                int k = s * 32 + kq + j;
                v[j] = (k < ICH) ? xr[k] : 0.0f;
            }
            af[s] = pack8(v);
        }
    }

    short* hgg = hg + (size_t)g * (HID * NPG);
    #pragma unroll
    for (int n = 0; n < 4; ++n) {
        floatx4 acc = {0.0f, 0.0f, 0.0f, 0.0f};
        #pragma unroll
        for (int s = 0; s < 5; ++s) {
            short8 b = *(const short8*)&W1T[(n * 16 + c16) * KP + s * 32 + kq];
            acc = __builtin_amdgcn_mfma_f32_16x16x32_bf16(af[s], b, acc, 0, 0, 0);
        }
        // D: row = (lane>>4)*4 + r, col = n*16 + c16  -> hg[col][row]
        int col = n * 16 + c16;
        int row = sub * 16 + (lane >> 4) * 4;
        *(int2*)&hgg[col * NPG + row] =
            make_int2((int)packbf(acc[0], acc[1]), (int)packbf(acc[2], acc[3]));
    }
}

// ---- kernel 2: aggregation + readout (As LDS only -> 4 blocks/CU) ----
__global__ __launch_bounds__(ATPB, 6) void gcn_agg(
    const int*   __restrict__ erow,    // [E]
    const int*   __restrict__ ecol,    // [E]
    const float* __restrict__ ew,      // [E]
    const short* __restrict__ hg,      // [B][64][128] bf16
    const float* __restrict__ b1,      // [64]
    const float* __restrict__ Wlin,    // [8192]
    const float* __restrict__ blin,    // [1]
    float* __restrict__ out)           // [B]
{
    __shared__ __align__(16) float As[64 * ASS];     // 33792 B
    __shared__ float deg[NPG];
    __shared__ float dinv[NPG];
    __shared__ float red[ATPB / 64];

    const int t    = threadIdx.x;
    const int g    = blockIdx.x;
    const int lane = t & 63;
    const int wv   = t >> 6;
    const int c16  = lane & 15;
    const int kq   = (lane >> 4) * 8;

    if (t < NPG) deg[t] = 1.0f;                      // self-loop weight

    // edges: one coalesced scan, packed into regs
    int   ep_[AEPT];                                 // (cl<<7) | rl
    float nw_[AEPT];
    const int ebase = g * EPG;
    #pragma unroll
    for (int it = 0; it < AEPT; ++it) {
        int e = ebase + t + it * ATPB;
        int rl = erow[e] & (NPG - 1);
        int cl = ecol[e] & (NPG - 1);
        ep_[it] = (cl << 7) | rl;
        nw_[it] = ew[e];
    }
    __syncthreads();                                  // bar1: deg init visible

    #pragma unroll
    for (int it = 0; it < AEPT; ++it)
        atomicAdd(&deg[ep_[it] >> 7], nw_[it]);
    __syncthreads();                                  // bar2: deg done

    if (t < NPG) dinv[t] = rsqrtf(deg[t]);            // deg >= 1 always
    __syncthreads();                                  // bar3: dinv ready

    #pragma unroll
    for (int it = 0; it < AEPT; ++it) {               // edge norms, once
        int rl = ep_[it] & (NPG - 1), cl = ep_[it] >> 7;
        nw_[it] = dinv[rl] * nw_[it] * dinv[cl];
    }

    float partial = 0.0f;
    const int mrow = (wv >> 1) * 16 + c16;            // dst row within half
    const short* hgg = hg + (size_t)g * (HID * NPG);

    for (int half = 0; half < 2; ++half) {
        for (int p = t; p < 64 * ASS / 4; p += ATPB)  // zero half-A
            ((floatx4*)As)[p] = (floatx4){0.0f, 0.0f, 0.0f, 0.0f};
        __syncthreads();                              // barA: zero done

        #pragma unroll
        for (int it = 0; it < AEPT; ++it) {
            int cl = ep_[it] >> 7;
            if ((cl >> 6) == half)
                atomicAdd(&As[(cl & 63) * ASS + (ep_[it] & (NPG - 1))], nw_[it]);
        }
        if (t < 64) {                                 // diagonal self-loop
            int i = half * 64 + t;
            atomicAdd(&As[t * ASS + i], dinv[i] * dinv[i]);
        }
        __syncthreads();                              // barB: As built

        short8 afr[4];                                // A frags -> bf16
        #pragma unroll
        for (int ks = 0; ks < 4; ++ks) {
            const float* ap = &As[mrow * ASS + ks * 32 + kq];
            floatx4 a0 = *(const floatx4*)ap;
            floatx4 a1 = *(const floatx4*)(ap + 4);
            float v[8] = {a0[0], a0[1], a0[2], a0[3], a1[0], a1[1], a1[2], a1[3]};
            afr[ks] = pack8(v);
        }
        #pragma unroll
        for (int nn = 0; nn < 2; ++nn) {
            int nt2 = (wv & 1) * 2 + nn;
            floatx4 acc = {0.0f, 0.0f, 0.0f, 0.0f};
            #pragma unroll
            for (int ks = 0; ks < 4; ++ks) {
                // B-frag: 8 consecutive src nodes of one channel, 16B global, L2-hot
                short8 b = *(const short8*)&hgg[(nt2 * 16 + c16) * NPG + ks * 32 + kq];
                acc = __builtin_amdgcn_mfma_f32_16x16x32_bf16(afr[ks], b, acc, 0, 0, 0);
            }
            int col = nt2 * 16 + c16;
            float b1v = b1[col];
            int node0 = half * 64 + (wv >> 1) * 16 + (lane >> 4) * 4;
            #pragma unroll
            for (int r = 0; r < 4; ++r) {
                float v = fmaxf(acc[r] + b1v, 0.0f);
                partial += v * Wlin[(node0 + r) * HID + col];
            }
        }
        __syncthreads();                              // barC: As reads done
    }

    #pragma unroll
    for (int o = 32; o > 0; o >>= 1)
        partial += __shfl_down(partial, o, 64);
    if (lane == 0) red[wv] = partial;
    __syncthreads();
    if (t == 0) {
        float tot = blin[0];
        #pragma unroll
        for (int i = 0; i < ATPB / 64; ++i) tot += red[i];
        out[g] = 1.0f / (1.0f + expf(-tot));
    }
}

extern "C" void kernel_launch(void* const* d_in, const int* in_sizes, int n_in,
                              void* d_out, int out_size, void* d_ws, size_t ws_size,
                              hipStream_t stream) {
    const float* x    = (const float*)d_in[0];
    const int*   ei   = (const int*)d_in[1];
    const float* ew   = (const float*)d_in[2];
    const float* W1   = (const float*)d_in[4];
    const float* b1   = (const float*)d_in[5];
    const float* Wlin = (const float*)d_in[6];
    const float* blin = (const float*)d_in[7];
    float* out = (float*)d_out;

    const int E = in_sizes[1] / 2;     // edge_index is [2, E]
    const int B = out_size;            // 2048 graphs

    short* W1T = (short*)d_ws;                        // 20480 B
    short* hg  = (short*)d_ws + HID * KP;             // [B][64][128] bf16 = 33.5 MB

    gcn_prep<<<(HID * KP + 511) / 512, 512, 0, stream>>>(W1, W1T);
    gcn_gemm<<<B * 2, 256, 0, stream>>>(x, W1T, hg);
    gcn_agg<<<B, ATPB, 0, stream>>>(ei, ei + E, ew, hg, b1, Wlin, blin, out);
}

// Round 15
// 102.443 us; speedup vs baseline: 1.3058x; 1.3058x over previous
//
#include <hip/hip_runtime.h>
#include <math.h>

#define NPG 128      // nodes per graph
#define HID 64
#define ICH 151
#define EPG 2048     // edges per graph
#define TPB 512      // 8 waves
#define EPT (EPG / TPB)
#define KP  160      // W1T padded K (5 MFMA k-steps of 32)
#define AS_OFF 16384 // byte offset of As region (= ht bytes: 64*128*2)

typedef __attribute__((ext_vector_type(8))) short  short8;   // bf16x8 frag
typedef __attribute__((ext_vector_type(4))) float  floatx4;  // f32x4 acc

// software fp32->bf16 RNE (proven R4/R6/R8/R10-R14; cvt_pk asm NaN'd R7/R9)
static __device__ __forceinline__ unsigned short f2bf(float v) {
    unsigned u = __builtin_bit_cast(unsigned, v);
    return (unsigned short)((u + 0x7fffu + ((u >> 16) & 1u)) >> 16);
}
static __device__ __forceinline__ unsigned packbf(float a, float b) {
    return (unsigned)f2bf(a) | ((unsigned)f2bf(b) << 16);
}
static __device__ __forceinline__ short8 pack8(const float* v) {
    union { unsigned u[4]; short8 s; } r;
    r.u[0] = packbf(v[0], v[1]);
    r.u[1] = packbf(v[2], v[3]);
    r.u[2] = packbf(v[4], v[5]);
    r.u[3] = packbf(v[6], v[7]);
    return r.s;
}

// ---- prep: W1 [151][64] f32 -> W1T [64][160] bf16 (k-pad zeroed) ----
__global__ __launch_bounds__(512) void gcn_prep(const float* __restrict__ W1,
                                                short* __restrict__ W1T) {
    int i = threadIdx.x + blockIdx.x * 512;          // 10240 elements exactly
    if (i < HID * KP) {
        int ch = i / KP, k = i - ch * KP;
        W1T[i] = (short)f2bf((k < ICH) ? W1[k * HID + ch] : 0.0f);
    }
}

__global__ __launch_bounds__(TPB, 6) void gcn_fused(
    const float* __restrict__ x,       // [N,151]
    const int*   __restrict__ erow,    // [E]
    const int*   __restrict__ ecol,    // [E]
    const float* __restrict__ ew,      // [E]
    const short* __restrict__ W1T,     // [64][160] bf16 (prepped)
    const float* __restrict__ b1,      // [64]
    const float* __restrict__ Wlin,    // [8192]
    const float* __restrict__ blin,    // [1]
    float* __restrict__ out)           // [B]
{
    // LDS 49152 B + ~1.1KB statics -> 3 blocks/CU.
    //   ht: 64x128 bf16, swizzled: elem(ch,node) at ch*128 + (node^((ch&7)<<3))
    //   As: 64x128 f32,  swizzled: elem(c,r)    at c*128  + (r^((c&7)<<2))
    __shared__ __align__(16) char smem[AS_OFF + 64 * 128 * 4];
    __shared__ float deg[NPG];
    __shared__ float dinv[NPG];
    __shared__ float red[TPB / 64];

    short* ht = (short*)smem;
    float* As = (float*)(smem + AS_OFF);

    const int t    = threadIdx.x;
    const int g    = blockIdx.x;
    const int lane = t & 63;
    const int wv   = t >> 6;
    const int c16  = lane & 15;
    const int kq   = (lane >> 4) * 8;

    if (t < NPG) deg[t] = 1.0f;                       // self-loop weight

    // ---- edges: one coalesced scan, packed into regs ----
    int   ep_[EPT];                                   // (cl<<7) | rl
    float nw_[EPT];                                   // ew, later norm
    const int ebase = g * EPG;
    #pragma unroll
    for (int it = 0; it < EPT; ++it) {
        int e = ebase + t + it * TPB;
        int rl = erow[e] & (NPG - 1);
        int cl = ecol[e] & (NPG - 1);
        ep_[it] = (cl << 7) | rl;
        nw_[it] = ew[e];
    }

    // ---- Wlin / b1 prefetch (removes global latency from epilogue) ----
    float wl[2][2][4];
    float b1v[2];
    {
        const int rbase = (wv >> 1) * 16 + (lane >> 4) * 4;
        #pragma unroll
        for (int nn = 0; nn < 2; ++nn) {
            int col = ((wv & 1) * 2 + nn) * 16 + c16;
            b1v[nn] = b1[col];
            #pragma unroll
            for (int half = 0; half < 2; ++half) {
                int node0 = half * 64 + rbase;
                #pragma unroll
                for (int r = 0; r < 4; ++r)
                    wl[half][nn][r] = Wlin[(node0 + r) * HID + col];
            }
        }
    }

    // ---- x A-fragments: direct guarded scalar loads (proven best) ----
    short8 af[5];
    {
        const float* xr = x + (size_t)g * (NPG * ICH) + (wv * 16 + c16) * ICH;
        #pragma unroll
        for (int s = 0; s < 5; ++s) {
            float v[8];
            #pragma unroll
            for (int j = 0; j < 8; ++j) {
                int k = s * 32 + kq + j;
                v[j] = (k < ICH) ? xr[k] : 0.0f;
            }
            af[s] = pack8(v);
        }
    }
    __syncthreads();                                   // bar1: deg-init visible

    // ---- interval 2: deg atomics + GEMM (global W1T B-frags) ----
    #pragma unroll
    for (int it = 0; it < EPT; ++it)
        atomicAdd(&deg[ep_[it] >> 7], nw_[it]);

    #pragma unroll
    for (int n = 0; n < 4; ++n) {
        floatx4 acc = {0.0f, 0.0f, 0.0f, 0.0f};
        #pragma unroll
        for (int s = 0; s < 5; ++s) {
            short8 b = *(const short8*)&W1T[(n * 16 + c16) * KP + s * 32 + kq];
            acc = __builtin_amdgcn_mfma_f32_16x16x32_bf16(af[s], b, acc, 0, 0, 0);
        }
        // D: row = (lane>>4)*4 + r, col = n*16 + c16 -> swizzled ht[col][row]
        int col = n * 16 + c16;
        int row = wv * 16 + (lane >> 4) * 4;
        *(int2*)&ht[col * 128 + (row ^ ((col & 7) << 3))] =
            make_int2((int)packbf(acc[0], acc[1]), (int)packbf(acc[2], acc[3]));
    }
    __syncthreads();                                   // bar2: deg + ht done

    // ---- interval 3: dinv + zero As (folded) ----
    if (t < NPG) dinv[t] = rsqrtf(deg[t]);             // deg >= 1 always
    #pragma unroll
    for (int p = 0; p < 4; ++p)                        // 2048 f32x4 = 64*128 f32
        ((floatx4*)As)[t + p * TPB] = (floatx4){0.0f, 0.0f, 0.0f, 0.0f};
    __syncthreads();                                   // bar3: dinv + zero0 ready

    // ---- interval 4: scatter half0 (norms inlined) + diag0 ----
    #pragma unroll
    for (int it = 0; it < EPT; ++it) {
        int rl = ep_[it] & (NPG - 1), cl = ep_[it] >> 7;
        float nrm = dinv[rl] * nw_[it] * dinv[cl];
        nw_[it] = nrm;                                 // keep for half1
        if ((cl >> 6) == 0)
            atomicAdd(&As[(cl & 63) * 128 + (rl ^ ((cl & 7) << 2))], nrm);
    }
    if (t < 64)
        atomicAdd(&As[t * 128 + (t ^ ((t & 7) << 2))], dinv[t] * dinv[t]);
    __syncthreads();                                   // bar4: As(half0) built

    float partial = 0.0f;
    const int mrow = (wv >> 1) * 16 + c16;             // dst row within half
    const int msw  = (mrow & 7) << 2;

    for (int half = 0; half < 2; ++half) {
        // ---- A-frags + MFMA + epilogue for this half ----
        short8 afr[4];
        #pragma unroll
        for (int ks = 0; ks < 4; ++ks) {
            int r0 = ks * 32 + kq;
            floatx4 a0 = *(const floatx4*)&As[mrow * 128 + (r0 ^ msw)];
            floatx4 a1 = *(const floatx4*)&As[mrow * 128 + ((r0 + 4) ^ msw)];
            float v[8] = {a0[0], a0[1], a0[2], a0[3], a1[0], a1[1], a1[2], a1[3]};
            afr[ks] = pack8(v);
        }
        #pragma unroll
        for (int nn = 0; nn < 2; ++nn) {
            int ch = ((wv & 1) * 2 + nn) * 16 + c16;
            int hsw = (ch & 7) << 3;
            floatx4 acc = {0.0f, 0.0f, 0.0f, 0.0f};
            #pragma unroll
            for (int ks = 0; ks < 4; ++ks) {
                short8 b = *(const short8*)&ht[ch * 128 + ((ks * 32 + kq) ^ hsw)];
                acc = __builtin_amdgcn_mfma_f32_16x16x32_bf16(afr[ks], b, acc, 0, 0, 0);
            }
            #pragma unroll
            for (int r = 0; r < 4; ++r) {
                float v = fmaxf(acc[r] + b1v[nn], 0.0f);
                partial += v * wl[half][nn][r];
            }
        }

        if (half == 0) {
            __syncthreads();                           // bar5: As reads done
            #pragma unroll
            for (int p = 0; p < 4; ++p)                // zero for half1
                ((floatx4*)As)[t + p * TPB] = (floatx4){0.0f, 0.0f, 0.0f, 0.0f};
            __syncthreads();                           // bar6: zero1 done

            #pragma unroll
            for (int it = 0; it < EPT; ++it) {         // scatter half1
                int rl = ep_[it] & (NPG - 1), cl = ep_[it] >> 7;
                if ((cl >> 6) == 1)
                    atomicAdd(&As[(cl & 63) * 128 + (rl ^ ((cl & 7) << 2))], nw_[it]);
            }
            if (t < 64) {
                int i = 64 + t;
                atomicAdd(&As[t * 128 + (i ^ ((t & 7) << 2))], dinv[i] * dinv[i]);
            }
            __syncthreads();                           // bar7: As(half1) built
        }
    }

    // ---- block reduction + sigmoid ----
    #pragma unroll
    for (int o = 32; o > 0; o >>= 1)
        partial += __shfl_down(partial, o, 64);
    if (lane == 0) red[wv] = partial;
    __syncthreads();                                   // bar8
    if (t == 0) {
        float tot = blin[0];
        #pragma unroll
        for (int i = 0; i < TPB / 64; ++i) tot += red[i];
        out[g] = 1.0f / (1.0f + expf(-tot));
    }
}

extern "C" void kernel_launch(void* const* d_in, const int* in_sizes, int n_in,
                              void* d_out, int out_size, void* d_ws, size_t ws_size,
                              hipStream_t stream) {
    const float* x    = (const float*)d_in[0];
    const int*   ei   = (const int*)d_in[1];
    const float* ew   = (const float*)d_in[2];
    const float* W1   = (const float*)d_in[4];
    const float* b1   = (const float*)d_in[5];
    const float* Wlin = (const float*)d_in[6];
    const float* blin = (const float*)d_in[7];
    float* out = (float*)d_out;

    const int E = in_sizes[1] / 2;     // edge_index is [2, E]
    const int B = out_size;            // 2048 graphs

    short* W1T = (short*)d_ws;         // [64][160] bf16 = 20480 B

    gcn_prep<<<(HID * KP + 511) / 512, 512, 0, stream>>>(W1, W1T);
    gcn_fused<<<B, TPB, 0, stream>>>(x, ei, ei + E, ew, W1T, b1, Wlin, blin, out);
}

// Round 16
// 100.780 us; speedup vs baseline: 1.3274x; 1.0165x over previous
//
#include <hip/hip_runtime.h>
#include <math.h>

#define NPG 128      // nodes per graph
#define HID 64
#define ICH 151
#define EPG 2048     // edges per graph
#define TPB 512      // 8 waves
#define EPT (EPG / TPB)
#define KP  160      // W1T padded K (5 MFMA k-steps of 32)
#define HTS 136      // h^T row stride, bf16 (272B: 16B-aligned, 2-way banks)
#define ASS 132      // As row stride, f32 (528B: 16B-aligned, 2-way banks)
#define AS_OFF 17408 // byte offset of As region (= ht bytes)

typedef __attribute__((ext_vector_type(8))) short  short8;   // bf16x8 frag
typedef __attribute__((ext_vector_type(4))) float  floatx4;  // f32x4 acc

// software fp32->bf16 RNE (proven R4/R6/R8/R10-R15; cvt_pk asm NaN'd R7/R9)
static __device__ __forceinline__ unsigned short f2bf(float v) {
    unsigned u = __builtin_bit_cast(unsigned, v);
    return (unsigned short)((u + 0x7fffu + ((u >> 16) & 1u)) >> 16);
}
static __device__ __forceinline__ unsigned packbf(float a, float b) {
    return (unsigned)f2bf(a) | ((unsigned)f2bf(b) << 16);
}
static __device__ __forceinline__ short8 pack8(const float* v) {
    union { unsigned u[4]; short8 s; } r;
    r.u[0] = packbf(v[0], v[1]);
    r.u[1] = packbf(v[2], v[3]);
    r.u[2] = packbf(v[4], v[5]);
    r.u[3] = packbf(v[6], v[7]);
    return r.s;
}

// ---- prep: W1 [151][64] f32 -> W1T [64][160] bf16 (k-pad zeroed) ----
__global__ __launch_bounds__(512) void gcn_prep(const float* __restrict__ W1,
                                                short* __restrict__ W1T) {
    int i = threadIdx.x + blockIdx.x * 512;          // 10240 elements exactly
    if (i < HID * KP) {
        int ch = i / KP, k = i - ch * KP;
        W1T[i] = (short)f2bf((k < ICH) ? W1[k * HID + ch] : 0.0f);
    }
}

__global__ __launch_bounds__(TPB, 6) void gcn_fused(
    const float* __restrict__ x,       // [N,151]
    const int*   __restrict__ erow,    // [E]
    const int*   __restrict__ ecol,    // [E]
    const float* __restrict__ ew,      // [E]
    const short* __restrict__ W1T,     // [64][160] bf16 (prepped)
    const float* __restrict__ b1,      // [64]
    const float* __restrict__ Wlin,    // [8192]
    const float* __restrict__ blin,    // [1]
    float* __restrict__ out)           // [B]
{
    // LDS 51200 B + ~0.6KB statics -> 3 blocks/CU:
    //   ht = smem[0 .. 17408)        64x136 bf16 h^T (GEMM out, agg B-frags)
    //   As = smem[17408 .. 51200)    64x132 f32 half-adjacency
    __shared__ __align__(16) char smem[AS_OFF + 64 * ASS * 4];
    __shared__ float deg[NPG];
    __shared__ float red[TPB / 64];

    short* ht = (short*)smem;
    float* As = (float*)(smem + AS_OFF);

    const int t    = threadIdx.x;
    const int g    = blockIdx.x;
    const int lane = t & 63;
    const int wv   = t >> 6;
    const int c16  = lane & 15;
    const int kq   = (lane >> 4) * 8;

    // ================= barrier-free preamble =================
    if (t < NPG) deg[t] = 1.0f;                       // self-loop weight

    // edges: one coalesced scan, packed into regs
    int   ep_[EPT];                                   // (cl<<7) | rl
    float nw_[EPT];                                   // ew, later norm
    const int ebase = g * EPG;
    #pragma unroll
    for (int it = 0; it < EPT; ++it) {
        int e = ebase + t + it * TPB;
        int rl = erow[e] & (NPG - 1);
        int cl = ecol[e] & (NPG - 1);
        ep_[it] = (cl << 7) | rl;
        nw_[it] = ew[e];
    }

    // x A-fragments: direct guarded scalar loads (proven best)
    short8 af[5];
    {
        const float* xr = x + (size_t)g * (NPG * ICH) + (wv * 16 + c16) * ICH;
        #pragma unroll
        for (int s = 0; s < 5; ++s) {
            float v[8];
            #pragma unroll
            for (int j = 0; j < 8; ++j) {
                int k = s * 32 + kq + j;
                v[j] = (k < ICH) ? xr[k] : 0.0f;
            }
            af[s] = pack8(v);
        }
    }

    // zero As for half0 (As region untouched by GEMM)
    for (int p = t; p < 64 * ASS / 4; p += TPB)
        ((floatx4*)As)[p] = (floatx4){0.0f, 0.0f, 0.0f, 0.0f};

    // GEMM h = x @ W1 -> ht (global W1T B-frags; no barrier needed)
    #pragma unroll
    for (int n = 0; n < 4; ++n) {
        floatx4 acc = {0.0f, 0.0f, 0.0f, 0.0f};
        #pragma unroll
        for (int s = 0; s < 5; ++s) {
            short8 b = *(const short8*)&W1T[(n * 16 + c16) * KP + s * 32 + kq];
            acc = __builtin_amdgcn_mfma_f32_16x16x32_bf16(af[s], b, acc, 0, 0, 0);
        }
        // D: row = (lane>>4)*4 + r, col = n*16 + c16  -> ht[col][row]
        int col = n * 16 + c16;
        int row = wv * 16 + (lane >> 4) * 4;
        *(int2*)&ht[col * HTS + row] =
            make_int2((int)packbf(acc[0], acc[1]), (int)packbf(acc[2], acc[3]));
    }
    __syncthreads();                                   // bar1: preamble done

    // ---- deg atomics ----
    #pragma unroll
    for (int it = 0; it < EPT; ++it)
        atomicAdd(&deg[ep_[it] >> 7], nw_[it]);
    __syncthreads();                                   // bar2: deg final

    // ---- scatter half0 (inline rsqrt norms) + diag0 ----
    #pragma unroll
    for (int it = 0; it < EPT; ++it) {
        int rl = ep_[it] & (NPG - 1), cl = ep_[it] >> 7;
        float nrm = rsqrtf(deg[rl]) * nw_[it] * rsqrtf(deg[cl]);
        nw_[it] = nrm;                                 // keep for half1
        if ((cl >> 6) == 0)
            atomicAdd(&As[(cl & 63) * ASS + rl], nrm);
    }
    if (t < 64)
        atomicAdd(&As[t * ASS + t], 1.0f / deg[t]);    // dinv^2 = 1/deg
    __syncthreads();                                   // bar3: As(half0) built

    // ---- A-frags half0 ----
    const int mrow = (wv >> 1) * 16 + c16;             // dst row within half
    short8 afr[4];
    #pragma unroll
    for (int ks = 0; ks < 4; ++ks) {
        const float* ap = &As[mrow * ASS + ks * 32 + kq];
        floatx4 a0 = *(const floatx4*)ap;
        floatx4 a1 = *(const floatx4*)(ap + 4);
        float v[8] = {a0[0], a0[1], a0[2], a0[3], a1[0], a1[1], a1[2], a1[3]};
        afr[ks] = pack8(v);
    }
    __syncthreads();                                   // bar4: As0 reads done

    // ---- zero half1 (issue first) then MFMA0 + epilogue0 overlap ----
    for (int p = t; p < 64 * ASS / 4; p += TPB)
        ((floatx4*)As)[p] = (floatx4){0.0f, 0.0f, 0.0f, 0.0f};

    float partial = 0.0f;
    #pragma unroll
    for (int nn = 0; nn < 2; ++nn) {
        int nt2 = (wv & 1) * 2 + nn;
        floatx4 acc = {0.0f, 0.0f, 0.0f, 0.0f};
        #pragma unroll
        for (int ks = 0; ks < 4; ++ks) {
            short8 b = *(const short8*)&ht[(nt2 * 16 + c16) * HTS + ks * 32 + kq];
            acc = __builtin_amdgcn_mfma_f32_16x16x32_bf16(afr[ks], b, acc, 0, 0, 0);
        }
        int col = nt2 * 16 + c16;
        float b1v = b1[col];
        int node0 = (wv >> 1) * 16 + (lane >> 4) * 4;  // half0
        #pragma unroll
        for (int r = 0; r < 4; ++r) {
            float v = fmaxf(acc[r] + b1v, 0.0f);
            partial += v * Wlin[(node0 + r) * HID + col];
        }
    }
    __syncthreads();                                   // bar5: zero1 done

    // ---- scatter half1 + diag1 ----
    #pragma unroll
    for (int it = 0; it < EPT; ++it) {
        int cl = ep_[it] >> 7;
        if ((cl >> 6) == 1)
            atomicAdd(&As[(cl & 63) * ASS + (ep_[it] & (NPG - 1))], nw_[it]);
    }
    if (t < 64)
        atomicAdd(&As[t * ASS + 64 + t], 1.0f / deg[64 + t]);
    __syncthreads();                                   // bar6: As(half1) built

    // ---- A-frags half1 + MFMA1 + epilogue1 ----
    #pragma unroll
    for (int ks = 0; ks < 4; ++ks) {
        const float* ap = &As[mrow * ASS + ks * 32 + kq];
        floatx4 a0 = *(const floatx4*)ap;
        floatx4 a1 = *(const floatx4*)(ap + 4);
        float v[8] = {a0[0], a0[1], a0[2], a0[3], a1[0], a1[1], a1[2], a1[3]};
        afr[ks] = pack8(v);
    }
    #pragma unroll
    for (int nn = 0; nn < 2; ++nn) {
        int nt2 = (wv & 1) * 2 + nn;
        floatx4 acc = {0.0f, 0.0f, 0.0f, 0.0f};
        #pragma unroll
        for (int ks = 0; ks < 4; ++ks) {
            short8 b = *(const short8*)&ht[(nt2 * 16 + c16) * HTS + ks * 32 + kq];
            acc = __builtin_amdgcn_mfma_f32_16x16x32_bf16(afr[ks], b, acc, 0, 0, 0);
        }
        int col = nt2 * 16 + c16;
        float b1v = b1[col];
        int node0 = 64 + (wv >> 1) * 16 + (lane >> 4) * 4;   // half1
        #pragma unroll
        for (int r = 0; r < 4; ++r) {
            float v = fmaxf(acc[r] + b1v, 0.0f);
            partial += v * Wlin[(node0 + r) * HID + col];
        }
    }

    // ---- block reduction + sigmoid ----
    #pragma unroll
    for (int o = 32; o > 0; o >>= 1)
        partial += __shfl_down(partial, o, 64);
    if (lane == 0) red[wv] = partial;
    __syncthreads();                                   // bar7
    if (t == 0) {
        float tot = blin[0];
        #pragma unroll
        for (int i = 0; i < TPB / 64; ++i) tot += red[i];
        out[g] = 1.0f / (1.0f + expf(-tot));
    }
}

extern "C" void kernel_launch(void* const* d_in, const int* in_sizes, int n_in,
                              void* d_out, int out_size, void* d_ws, size_t ws_size,
                              hipStream_t stream) {
    const float* x    = (const float*)d_in[0];
    const int*   ei   = (const int*)d_in[1];
    const float* ew   = (const float*)d_in[2];
    const float* W1   = (const float*)d_in[4];
    const float* b1   = (const float*)d_in[5];
    const float* Wlin = (const float*)d_in[6];
    const float* blin = (const float*)d_in[7];
    float* out = (float*)d_out;

    const int E = in_sizes[1] / 2;     // edge_index is [2, E]
    const int B = out_size;            // 2048 graphs

    short* W1T = (short*)d_ws;         // [64][160] bf16 = 20480 B

    gcn_prep<<<(HID * KP + 511) / 512, 512, 0, stream>>>(W1, W1T);
    gcn_fused<<<B, TPB, 0, stream>>>(x, ei, ei + E, ew, W1T, b1, Wlin, blin, out);
}

// Round 17
// 84.145 us; speedup vs baseline: 1.5898x; 1.1977x over previous
//
#include <hip/hip_runtime.h>
#include <math.h>

#define NPG 128      // nodes per graph
#define HID 64
#define ICH 151
#define EPG 2048     // edges per graph
#define TPB 512      // 8 waves
#define EPT (EPG / TPB)
#define KP  160      // W1T padded K (5 MFMA k-steps of 32)
#define HTS 136      // h^T row stride, bf16 (272B: 16B-aligned, 2-way banks)
#define ASS 132      // As row stride, f32 (528B: 16B-aligned, 2-way banks)
#define AS_OFF 17408 // byte offset of As region (= ht bytes)

typedef __attribute__((ext_vector_type(8))) short  short8;   // bf16x8 frag
typedef __attribute__((ext_vector_type(4))) float  floatx4;  // f32x4 acc

// software fp32->bf16 RNE (proven R4/R6/R8/R10-R16; cvt_pk asm NaN'd R7/R9)
static __device__ __forceinline__ unsigned short f2bf(float v) {
    unsigned u = __builtin_bit_cast(unsigned, v);
    return (unsigned short)((u + 0x7fffu + ((u >> 16) & 1u)) >> 16);
}
static __device__ __forceinline__ unsigned packbf(float a, float b) {
    return (unsigned)f2bf(a) | ((unsigned)f2bf(b) << 16);
}
static __device__ __forceinline__ short8 pack8(const float* v) {
    union { unsigned u[4]; short8 s; } r;
    r.u[0] = packbf(v[0], v[1]);
    r.u[1] = packbf(v[2], v[3]);
    r.u[2] = packbf(v[4], v[5]);
    r.u[3] = packbf(v[6], v[7]);
    return r.s;
}

// ---- prep: W1 [151][64] f32 -> W1T [64][160] bf16 (k-pad zeroed) ----
__global__ __launch_bounds__(512) void gcn_prep(const float* __restrict__ W1,
                                                short* __restrict__ W1T) {
    int i = threadIdx.x + blockIdx.x * 512;          // 10240 elements exactly
    if (i < HID * KP) {
        int ch = i / KP, k = i - ch * KP;
        W1T[i] = (short)f2bf((k < ICH) ? W1[k * HID + ch] : 0.0f);
    }
}

__global__ __launch_bounds__(TPB, 6) void gcn_fused(
    const float* __restrict__ x,       // [N,151]
    const int*   __restrict__ erow,    // [E]
    const int*   __restrict__ ecol,    // [E]
    const float* __restrict__ ew,      // [E]
    const short* __restrict__ W1T,     // [64][160] bf16 (prepped)
    const float* __restrict__ b1,      // [64]
    const float* __restrict__ Wlin,    // [8192]
    const float* __restrict__ blin,    // [1]
    float* __restrict__ out)           // [B]
{
    // LDS 51200 B + ~0.6KB statics -> 3 blocks/CU:
    //   ht = smem[0 .. 17408)        64x136 bf16 h^T (GEMM out, agg B-frags)
    //   As = smem[17408 .. 51200)    64x132 f32 RAW half-adjacency
    __shared__ __align__(16) char smem[AS_OFF + 64 * ASS * 4];
    __shared__ float deg[NPG];
    __shared__ float red[TPB / 64];

    short* ht = (short*)smem;
    float* As = (float*)(smem + AS_OFF);

    const int t    = threadIdx.x;
    const int g    = blockIdx.x;
    const int lane = t & 63;
    const int wv   = t >> 6;
    const int c16  = lane & 15;
    const int kq   = (lane >> 4) * 8;

    // ---- tiny preamble: deg init + zero As(half0) ----
    if (t < NPG) deg[t] = 1.0f;                       // self-loop weight
    for (int p = t; p < 64 * ASS / 4; p += TPB)
        ((floatx4*)As)[p] = (floatx4){0.0f, 0.0f, 0.0f, 0.0f};
    __syncthreads();                                   // bar0 (cheap, early)

    // ================= I1: the fat interval =================
    // edges -> regs (issued first: oldest in vmcnt queue)
    int   ep_[EPT];                                    // (cl<<7) | rl
    float nw_[EPT];                                    // raw w
    const int ebase = g * EPG;
    #pragma unroll
    for (int it = 0; it < EPT; ++it) {
        int e = ebase + t + it * TPB;
        int rl = erow[e] & (NPG - 1);
        int cl = ecol[e] & (NPG - 1);
        ep_[it] = (cl << 7) | rl;
        nw_[it] = ew[e];
    }

    // x A-fragments: direct guarded scalar loads (proven best)
    short8 af[5];
    {
        const float* xr = x + (size_t)g * (NPG * ICH) + (wv * 16 + c16) * ICH;
        #pragma unroll
        for (int s = 0; s < 5; ++s) {
            float v[8];
            #pragma unroll
            for (int j = 0; j < 8; ++j) {
                int k = s * 32 + kq + j;
                v[j] = (k < ICH) ? xr[k] : 0.0f;
            }
            af[s] = pack8(v);
        }
    }

    // deg atomics + RAW scatter half0 + diag0 (no deg dependency!)
    #pragma unroll
    for (int it = 0; it < EPT; ++it) {
        int rl = ep_[it] & (NPG - 1), cl = ep_[it] >> 7;
        atomicAdd(&deg[cl], nw_[it]);
        if ((cl >> 6) == 0)
            atomicAdd(&As[(cl & 63) * ASS + rl], nw_[it]);
    }
    if (t < 64)
        atomicAdd(&As[t * ASS + t], 1.0f);             // raw self-loop

    // GEMM h = x @ W1 -> ht (global W1T B-frags) — hides the atomics above
    #pragma unroll
    for (int n = 0; n < 4; ++n) {
        floatx4 acc = {0.0f, 0.0f, 0.0f, 0.0f};
        #pragma unroll
        for (int s = 0; s < 5; ++s) {
            short8 b = *(const short8*)&W1T[(n * 16 + c16) * KP + s * 32 + kq];
            acc = __builtin_amdgcn_mfma_f32_16x16x32_bf16(af[s], b, acc, 0, 0, 0);
        }
        int col = n * 16 + c16;
        int row = wv * 16 + (lane >> 4) * 4;
        *(int2*)&ht[col * HTS + row] =
            make_int2((int)packbf(acc[0], acc[1]), (int)packbf(acc[2], acc[3]));
    }
    __syncthreads();                                   // bar1: deg/As0/ht final

    // ================= I2: half0 frags + MFMA + relu =================
    const int mrow  = (wv >> 1) * 16 + c16;            // dst row within half
    const int rbase = (wv >> 1) * 16 + (lane >> 4) * 4;
    float v0[2][4];                                    // relu outputs, half0

    {
        short8 afr[4];
        #pragma unroll
        for (int ks = 0; ks < 4; ++ks) {               // col-scale by dinv[src]
            const float* ap = &As[mrow * ASS + ks * 32 + kq];
            floatx4 a0 = *(const floatx4*)ap;
            floatx4 a1 = *(const floatx4*)(ap + 4);
            floatx4 d0 = *(const floatx4*)&deg[ks * 32 + kq];
            floatx4 d1 = *(const floatx4*)&deg[ks * 32 + kq + 4];
            float v[8];
            #pragma unroll
            for (int j = 0; j < 4; ++j) {
                v[j]     = a0[j] * rsqrtf(d0[j]);
                v[4 + j] = a1[j] * rsqrtf(d1[j]);
            }
            afr[ks] = pack8(v);
        }
        float rs[4];
        #pragma unroll
        for (int r = 0; r < 4; ++r)                    // row-scale dinv[dst]
            rs[r] = rsqrtf(deg[rbase + r]);
        #pragma unroll
        for (int nn = 0; nn < 2; ++nn) {
            int col = ((wv & 1) * 2 + nn) * 16 + c16;
            floatx4 acc = {0.0f, 0.0f, 0.0f, 0.0f};
            #pragma unroll
            for (int ks = 0; ks < 4; ++ks) {
                short8 b = *(const short8*)&ht[col * HTS + ks * 32 + kq];
                acc = __builtin_amdgcn_mfma_f32_16x16x32_bf16(afr[ks], b, acc, 0, 0, 0);
            }
            float b1v = b1[col];
            #pragma unroll
            for (int r = 0; r < 4; ++r)
                v0[nn][r] = fmaxf(acc[r] * rs[r] + b1v, 0.0f);
        }
    }
    __syncthreads();                                   // bar2: As0 reads done

    // ================= I3: zero As(half1) + deferred Wlin0 dot ==========
    for (int p = t; p < 64 * ASS / 4; p += TPB)
        ((floatx4*)As)[p] = (floatx4){0.0f, 0.0f, 0.0f, 0.0f};
    float partial = 0.0f;
    #pragma unroll
    for (int nn = 0; nn < 2; ++nn) {                   // global loads hide zeroing
        int col = ((wv & 1) * 2 + nn) * 16 + c16;
        #pragma unroll
        for (int r = 0; r < 4; ++r)
            partial += v0[nn][r] * Wlin[(rbase + r) * HID + col];
    }
    __syncthreads();                                   // bar3: zero1 done

    // ================= I4: scatter half1 (small) =================
    #pragma unroll
    for (int it = 0; it < EPT; ++it) {
        int cl = ep_[it] >> 7;
        if ((cl >> 6) == 1)
            atomicAdd(&As[(cl & 63) * ASS + (ep_[it] & (NPG - 1))], nw_[it]);
    }
    if (t < 64)
        atomicAdd(&As[t * ASS + 64 + t], 1.0f);        // raw self-loop
    __syncthreads();                                   // bar4: As1 built

    // ================= I5: half1 frags + MFMA + epilogue + reduce =======
    {
        short8 afr[4];
        #pragma unroll
        for (int ks = 0; ks < 4; ++ks) {
            const float* ap = &As[mrow * ASS + ks * 32 + kq];
            floatx4 a0 = *(const floatx4*)ap;
            floatx4 a1 = *(const floatx4*)(ap + 4);
            floatx4 d0 = *(const floatx4*)&deg[ks * 32 + kq];
            floatx4 d1 = *(const floatx4*)&deg[ks * 32 + kq + 4];
            float v[8];
            #pragma unroll
            for (int j = 0; j < 4; ++j) {
                v[j]     = a0[j] * rsqrtf(d0[j]);
                v[4 + j] = a1[j] * rsqrtf(d1[j]);
            }
            afr[ks] = pack8(v);
        }
        float rs[4];
        #pragma unroll
        for (int r = 0; r < 4; ++r)
            rs[r] = rsqrtf(deg[64 + rbase + r]);
        #pragma unroll
        for (int nn = 0; nn < 2; ++nn) {
            int col = ((wv & 1) * 2 + nn) * 16 + c16;
            floatx4 acc = {0.0f, 0.0f, 0.0f, 0.0f};
            #pragma unroll
            for (int ks = 0; ks < 4; ++ks) {
                short8 b = *(const short8*)&ht[col * HTS + ks * 32 + kq];
                acc = __builtin_amdgcn_mfma_f32_16x16x32_bf16(afr[ks], b, acc, 0, 0, 0);
            }
            float b1v = b1[col];
            #pragma unroll
            for (int r = 0; r < 4; ++r) {
                float v = fmaxf(acc[r] * rs[r] + b1v, 0.0f);
                partial += v * Wlin[(64 + rbase + r) * HID + col];
            }
        }
    }

    // ---- block reduction + sigmoid ----
    #pragma unroll
    for (int o = 32; o > 0; o >>= 1)
        partial += __shfl_down(partial, o, 64);
    if (lane == 0) red[wv] = partial;
    __syncthreads();                                   // bar5
    if (t == 0) {
        float tot = blin[0];
        #pragma unroll
        for (int i = 0; i < TPB / 64; ++i) tot += red[i];
        out[g] = 1.0f / (1.0f + expf(-tot));
    }
}

extern "C" void kernel_launch(void* const* d_in, const int* in_sizes, int n_in,
                              void* d_out, int out_size, void* d_ws, size_t ws_size,
                              hipStream_t stream) {
    const float* x    = (const float*)d_in[0];
    const int*   ei   = (const int*)d_in[1];
    const float* ew   = (const float*)d_in[2];
    const float* W1   = (const float*)d_in[4];
    const float* b1   = (const float*)d_in[5];
    const float* Wlin = (const float*)d_in[6];
    const float* blin = (const float*)d_in[7];
    float* out = (float*)d_out;

    const int E = in_sizes[1] / 2;     // edge_index is [2, E]
    const int B = out_size;            // 2048 graphs

    short* W1T = (short*)d_ws;         // [64][160] bf16 = 20480 B

    gcn_prep<<<(HID * KP + 511) / 512, 512, 0, stream>>>(W1, W1T);
    gcn_fused<<<B, TPB, 0, stream>>>(x, ei, ei + E, ew, W1T, b1, Wlin, blin, out);
}